// Round 10
// baseline (417.459 us; speedup 1.0000x reference)
//
#include <hip/hip_runtime.h>
#include <hip/hip_bf16.h>

// N=50000, E=1600000, F0=256, F1=256, F2=128
// R9: place_kernel is #1 (80us) with 9x write amplification (116MB for 12.8MB
// payload) == one flush per XCD per line -> blockIdx%8 is NOT the XCD map
// (also explains R5). R10: drop wsrc entirely — R4 vs R6 measured that inline
// dinv[s] loads in agg are identical to streamed weights, so wsrc only added
// 6.4MB of 9x-amplified scatter. place now writes ssrc only.

typedef __bf16 bf16x8 __attribute__((ext_vector_type(8)));
typedef float f32x4 __attribute__((ext_vector_type(4)));
typedef float f32x2 __attribute__((ext_vector_type(2)));

__device__ inline unsigned short f2bf(float f) {
    unsigned u = __float_as_uint(f);
    u += 0x7FFFu + ((u >> 16) & 1u);  // RNE
    return (unsigned short)(u >> 16);
}
__device__ inline float bf16lo(unsigned q) { return __uint_as_float(q << 16); }
__device__ inline float bf16hi(unsigned q) { return __uint_as_float(q & 0xFFFF0000u); }

#define XCDS 8

// ---------------- CSR build (8-sweep partition: temporal clustering, amp 16x->9x) ----------------

__global__ __launch_bounds__(256) void count_kernel_x(const int* __restrict__ dst,
                                                      int* __restrict__ cnt, int E, int ng) {
    int g = blockIdx.x & (XCDS - 1);
    int lo = g * ng, hi = lo + ng;
    int bid = blockIdx.x >> 3;
    int stride = (gridDim.x >> 3) * 256;
    for (int e = bid * 256 + threadIdx.x; e < E; e += stride) {
        int d = dst[e];
        if (d >= lo && d < hi) atomicAdd(&cnt[d], 1);
    }
}

__global__ __launch_bounds__(256) void place_kernel_x(const int* __restrict__ src,
                                                      const int* __restrict__ dst,
                                                      int* __restrict__ cursor,
                                                      int* __restrict__ ssrc, int E, int ng) {
    int g = blockIdx.x & (XCDS - 1);
    int lo = g * ng, hi = lo + ng;
    int bid = blockIdx.x >> 3;
    int stride = (gridDim.x >> 3) * 256;
    for (int e = bid * 256 + threadIdx.x; e < E; e += stride) {
        int d = dst[e];
        if (d >= lo && d < hi) {
            int p = atomicAdd(&cursor[d], 1);
            ssrc[p] = src[e];
        }
    }
}

// ---------------- hierarchical scan ----------------

__global__ __launch_bounds__(256) void scan_partial_kernel(const int* __restrict__ cnt,
                                                           int* __restrict__ bsum, int n) {
    __shared__ int s[256];
    int i0 = blockIdx.x * 1024 + threadIdx.x * 4;
    int lsum = 0;
#pragma unroll
    for (int j = 0; j < 4; ++j)
        if (i0 + j < n) lsum += cnt[i0 + j];
    s[threadIdx.x] = lsum;
    __syncthreads();
    for (int off = 128; off > 0; off >>= 1) {
        if (threadIdx.x < off) s[threadIdx.x] += s[threadIdx.x + off];
        __syncthreads();
    }
    if (threadIdx.x == 0) bsum[blockIdx.x] = s[0];
}

__global__ __launch_bounds__(256) void scan_finalize_kernel(const int* __restrict__ cnt,
                                                            const int* __restrict__ bsum,
                                                            int* __restrict__ offs,
                                                            float* __restrict__ dinv,
                                                            int* __restrict__ cursor,
                                                            int n, int nb) {
    __shared__ int s[256];
    __shared__ int bpre_s;
    if (threadIdx.x == 0) {
        int r = 0;
        for (int b = 0; b < (int)blockIdx.x; ++b) r += bsum[b];
        bpre_s = r;
    }
    int i0 = blockIdx.x * 1024 + threadIdx.x * 4;
    int v[4];
#pragma unroll
    for (int j = 0; j < 4; ++j) v[j] = (i0 + j < n) ? cnt[i0 + j] : 0;
    int lsum = v[0] + v[1] + v[2] + v[3];
    s[threadIdx.x] = lsum;
    __syncthreads();
    for (int off = 1; off < 256; off <<= 1) {
        int t = (threadIdx.x >= off) ? s[threadIdx.x - off] : 0;
        __syncthreads();
        s[threadIdx.x] += t;
        __syncthreads();
    }
    int run = s[threadIdx.x] - lsum + bpre_s;
    if (blockIdx.x == 0 && threadIdx.x == 0) offs[0] = 0;
#pragma unroll
    for (int j = 0; j < 4; ++j) {
        int i = i0 + j;
        if (i < n) {
            cursor[i] = run;
            dinv[i] = rsqrtf((float)(v[j] + 1));
            run += v[j];
            offs[i + 1] = run;
        }
    }
}

// ---------------- weight transpose+cast ----------------

__global__ void transpose_cast2_kernel(const float* __restrict__ W1,
                                       unsigned short* __restrict__ Wt1,
                                       const float* __restrict__ W2,
                                       unsigned short* __restrict__ Wt2) {
    int b = blockIdx.x;
    if (b < 256) {
        for (int k = threadIdx.x; k < 256; k += 64)
            Wt1[(size_t)b * 256 + k] = f2bf(W1[(size_t)k * 256 + b]);
    } else {
        int n = b - 256;
        for (int k = threadIdx.x; k < 256; k += 64)
            Wt2[(size_t)n * 256 + k] = f2bf(W2[(size_t)k * 128 + n]);
    }
}

// ---------------- bf16 MFMA GEMM ----------------
// AFP32: A fp32, cast to bf16 in-register during staging. OUT8: C stored fp8-e4m3.

template <int BN, bool AFP32, bool OUT8>
__global__ __launch_bounds__(256) void gemm_mfma_kernel(const void* __restrict__ Av,
                                                        const unsigned short* __restrict__ Bt,
                                                        void* __restrict__ Cv,
                                                        int M, int K, int N) {
    constexpr int BM = 128, BK = 32, LDA = BK + 8;
    constexpr int CT = BN / 16;
    __shared__ unsigned short As[BM][LDA];
    __shared__ unsigned short Bs[BN][LDA];
    int tid = threadIdx.x;
    int wave = tid >> 6, lane = tid & 63;
    int quad = lane >> 4, l16 = lane & 15;
    int row0 = blockIdx.x * BM, col0 = blockIdx.y * BN;

    f32x4 acc[2][CT];
#pragma unroll
    for (int i = 0; i < 2; ++i)
#pragma unroll
        for (int j = 0; j < CT; ++j) acc[i][j] = (f32x4){0.f, 0.f, 0.f, 0.f};

    int ar = tid >> 2;
    int ac = (tid & 3) * 8;

    for (int k0 = 0; k0 < K; k0 += BK) {
#pragma unroll
        for (int i = 0; i < 2; ++i) {
            int r = ar + i * 64;
            int gr = row0 + r;
            uint4 v = make_uint4(0u, 0u, 0u, 0u);
            if (gr < M) {
                if constexpr (AFP32) {
                    const float* A = (const float*)Av;
                    float4 a = *(const float4*)&A[(size_t)gr * K + k0 + ac];
                    float4 b = *(const float4*)&A[(size_t)gr * K + k0 + ac + 4];
                    v.x = (unsigned)f2bf(a.x) | ((unsigned)f2bf(a.y) << 16);
                    v.y = (unsigned)f2bf(a.z) | ((unsigned)f2bf(a.w) << 16);
                    v.z = (unsigned)f2bf(b.x) | ((unsigned)f2bf(b.y) << 16);
                    v.w = (unsigned)f2bf(b.z) | ((unsigned)f2bf(b.w) << 16);
                } else {
                    const unsigned short* A = (const unsigned short*)Av;
                    v = *(const uint4*)&A[(size_t)gr * K + k0 + ac];
                }
            }
            *(uint4*)&As[r][ac] = v;
        }
#pragma unroll
        for (int i = 0; i < BN / 64; ++i) {
            int r = ar + i * 64;
            *(uint4*)&Bs[r][ac] = *(const uint4*)&Bt[(size_t)(col0 + r) * K + k0 + ac];
        }
        __syncthreads();
        bf16x8 af[2];
#pragma unroll
        for (int tr = 0; tr < 2; ++tr)
            af[tr] = *(const bf16x8*)&As[wave * 32 + tr * 16 + l16][quad * 8];
#pragma unroll
        for (int tc = 0; tc < CT; ++tc) {
            bf16x8 bf = *(const bf16x8*)&Bs[tc * 16 + l16][quad * 8];
            acc[0][tc] = __builtin_amdgcn_mfma_f32_16x16x32_bf16(af[0], bf, acc[0][tc], 0, 0, 0);
            acc[1][tc] = __builtin_amdgcn_mfma_f32_16x16x32_bf16(af[1], bf, acc[1][tc], 0, 0, 0);
        }
        __syncthreads();
    }
#pragma unroll
    for (int tr = 0; tr < 2; ++tr) {
        int gr0 = row0 + wave * 32 + tr * 16 + quad * 4;
#pragma unroll
        for (int tc = 0; tc < CT; ++tc) {
            int gc = col0 + tc * 16 + l16;
#pragma unroll
            for (int j = 0; j < 4; ++j) {
                int gr = gr0 + j;
                if (gr < M) {
                    if constexpr (OUT8) {
                        unsigned char* C = (unsigned char*)Cv;
                        int p = __builtin_amdgcn_cvt_pk_fp8_f32(acc[tr][tc][j], 0.f, 0, false);
                        C[(size_t)gr * N + gc] = (unsigned char)(p & 0xFF);
                    } else {
                        unsigned short* C = (unsigned short*)Cv;
                        C[(size_t)gr * N + gc] = f2bf(acc[tr][tc][j]);
                    }
                }
            }
        }
    }
}

// ---------------- agg1: fp8 gather (F=256), inline dinv, bf16 out, ReLU ----------------

__global__ __launch_bounds__(256) void agg_fp8_kernel(const unsigned char* __restrict__ h,
                                                      const float* __restrict__ dinv,
                                                      const int* __restrict__ offs,
                                                      const int* __restrict__ ssrc,
                                                      const float* __restrict__ bias,
                                                      unsigned short* __restrict__ out, int N) {
    constexpr int F = 256;
    int n = blockIdx.x * 4 + (threadIdx.x >> 6);
    if (n >= N) return;
    int lane = threadIdx.x & 63;
    int c = lane * 4;
    float di = dinv[n];
    float acc[4];

    auto dec_fma = [&](unsigned q, float w, float* a) {
        f32x2 lo = __builtin_amdgcn_cvt_pk_f32_fp8(q, false);
        f32x2 hi = __builtin_amdgcn_cvt_pk_f32_fp8(q, true);
        a[0] = fmaf(w, lo.x, a[0]);
        a[1] = fmaf(w, lo.y, a[1]);
        a[2] = fmaf(w, hi.x, a[2]);
        a[3] = fmaf(w, hi.y, a[3]);
    };

    {
        unsigned q = *(const unsigned*)&h[(size_t)n * F + c];
        f32x2 lo = __builtin_amdgcn_cvt_pk_f32_fp8(q, false);
        f32x2 hi = __builtin_amdgcn_cvt_pk_f32_fp8(q, true);
        acc[0] = di * lo.x; acc[1] = di * lo.y;
        acc[2] = di * hi.x; acc[3] = di * hi.y;
    }

    int e = offs[n], e1 = offs[n + 1];
    for (; e + 8 <= e1; e += 8) {
        int   s[8];
        float w[8];
        unsigned q[8];
#pragma unroll
        for (int j = 0; j < 8; ++j) s[j] = ssrc[e + j];
#pragma unroll
        for (int j = 0; j < 8; ++j) w[j] = dinv[s[j]];
#pragma unroll
        for (int j = 0; j < 8; ++j) q[j] = *(const unsigned*)&h[(size_t)s[j] * F + c];
#pragma unroll
        for (int j = 0; j < 8; ++j) dec_fma(q[j], w[j], acc);
    }
    for (; e < e1; ++e) {
        int s = ssrc[e];
        unsigned q = *(const unsigned*)&h[(size_t)s * F + c];
        dec_fma(q, dinv[s], acc);
    }

#pragma unroll
    for (int v = 0; v < 4; ++v) {
        float r = fmaf(acc[v], di, bias[c + v]);
        acc[v] = fmaxf(r, 0.f);
    }
    uint2 p;
    p.x = (unsigned)f2bf(acc[0]) | ((unsigned)f2bf(acc[1]) << 16);
    p.y = (unsigned)f2bf(acc[2]) | ((unsigned)f2bf(acc[3]) << 16);
    *(uint2*)&out[(size_t)n * F + c] = p;
}

// ---------------- agg2: bf16 gather (F=128), inline dinv, fp32 out ----------------

__global__ __launch_bounds__(256) void agg_bf16_kernel(const unsigned short* __restrict__ h,
                                                       const float* __restrict__ dinv,
                                                       const int* __restrict__ offs,
                                                       const int* __restrict__ ssrc,
                                                       const float* __restrict__ bias,
                                                       float* __restrict__ out, int N) {
    constexpr int F = 128;
    int n = blockIdx.x * 4 + (threadIdx.x >> 6);
    if (n >= N) return;
    int lane = threadIdx.x & 63;
    int c = lane * 2;
    float di = dinv[n];
    float a0, a1;
    {
        unsigned q = *(const unsigned*)&h[(size_t)n * F + c];
        a0 = di * bf16lo(q); a1 = di * bf16hi(q);
    }
    int e = offs[n], e1 = offs[n + 1];
    for (; e + 8 <= e1; e += 8) {
        int   s[8];
        float w[8];
        unsigned q[8];
#pragma unroll
        for (int j = 0; j < 8; ++j) s[j] = ssrc[e + j];
#pragma unroll
        for (int j = 0; j < 8; ++j) w[j] = dinv[s[j]];
#pragma unroll
        for (int j = 0; j < 8; ++j) q[j] = *(const unsigned*)&h[(size_t)s[j] * F + c];
#pragma unroll
        for (int j = 0; j < 8; ++j) {
            a0 = fmaf(w[j], bf16lo(q[j]), a0);
            a1 = fmaf(w[j], bf16hi(q[j]), a1);
        }
    }
    for (; e < e1; ++e) {
        int s = ssrc[e];
        unsigned q = *(const unsigned*)&h[(size_t)s * F + c];
        float w = dinv[s];
        a0 = fmaf(w, bf16lo(q), a0);
        a1 = fmaf(w, bf16hi(q), a1);
    }
    float r0 = fmaf(a0, di, bias[c]);
    float r1 = fmaf(a1, di, bias[c + 1]);
    *(float2*)&out[(size_t)n * F + c] = make_float2(r0, r1);
}

// ---------------- launch ----------------

extern "C" void kernel_launch(void* const* d_in, const int* in_sizes, int n_in,
                              void* d_out, int out_size, void* d_ws, size_t ws_size,
                              hipStream_t stream) {
    const float* x  = (const float*)d_in[0];
    const int*   ei = (const int*)d_in[1];
    const float* W1 = (const float*)d_in[2];
    const float* b1 = (const float*)d_in[3];
    const float* W2 = (const float*)d_in[4];
    const float* b2 = (const float*)d_in[5];
    float* out = (float*)d_out;

    const int F0 = 256, F1 = 256, F2 = 128;
    const int N = in_sizes[0] / F0;   // 50000
    const int E = in_sizes[1] / 2;    // 1600000
    const int* src = ei;
    const int* dst = ei + E;
    const int ng = (N + XCDS - 1) / XCDS;
    const int NB = (N + 1023) / 1024;

    char* ws = (char*)d_ws;
    size_t off = 0;
    auto alloc = [&](size_t bytes) {
        char* p = ws + off;
        off += (bytes + 255) & ~(size_t)255;
        return p;
    };
    int*            cnt    = (int*)alloc((size_t)N * 4);
    int*            offs   = (int*)alloc((size_t)(N + 1) * 4);
    int*            cursor = (int*)alloc((size_t)N * 4);
    float*          dinv   = (float*)alloc((size_t)N * 4);
    int*            bsum   = (int*)alloc((size_t)NB * 4);
    int*            ssrc   = (int*)alloc((size_t)E * 4);
    unsigned short* wt1    = (unsigned short*)alloc((size_t)F1 * F0 * 2);
    unsigned short* wt2    = (unsigned short*)alloc((size_t)F2 * F1 * 2);
    unsigned char*  h1     = (unsigned char*)alloc((size_t)N * F1);      // fp8
    unsigned short* h1a    = (unsigned short*)alloc((size_t)N * F1 * 2); // bf16
    unsigned short* h2     = (unsigned short*)alloc((size_t)N * F2 * 2); // bf16
    (void)ws_size; (void)n_in; (void)out_size;

    // CSR build
    hipMemsetAsync(cnt, 0, (size_t)N * 4, stream);
    count_kernel_x<<<2048, 256, 0, stream>>>(dst, cnt, E, ng);
    scan_partial_kernel<<<NB, 256, 0, stream>>>(cnt, bsum, N);
    scan_finalize_kernel<<<NB, 256, 0, stream>>>(cnt, bsum, offs, dinv, cursor, N, NB);
    place_kernel_x<<<2048, 256, 0, stream>>>(src, dst, cursor, ssrc, E, ng);

    // weights
    transpose_cast2_kernel<<<384, 64, 0, stream>>>(W1, wt1, W2, wt2);

    // layer 1: h1(fp8) = x @ W1 ; h1a(bf16) = relu(agg(h1))
    {
        dim3 grid((N + 127) / 128, F1 / 128);
        gemm_mfma_kernel<128, true, true><<<grid, 256, 0, stream>>>(x, wt1, h1, N, F0, F1);
    }
    agg_fp8_kernel<<<(N + 3) / 4, 256, 0, stream>>>(h1, dinv, offs, ssrc, b1, h1a, N);

    // layer 2: h2(bf16) = h1a @ W2 ; out(fp32) = agg(h2)
    {
        dim3 grid((N + 127) / 128, F2 / 64);
        gemm_mfma_kernel<64, false, false><<<grid, 256, 0, stream>>>(h1a, wt2, h2, N, F1, F2);
    }
    agg_bf16_kernel<<<(N + 3) / 4, 256, 0, stream>>>(h2, dinv, offs, ssrc, b2, out, N);
}